// Round 1
// baseline (746.885 us; speedup 1.0000x reference)
//
#include <hip/hip_runtime.h>
#include <hip/hip_bf16.h>

#define BATCH 32
#define T 1024
#define BIGF 1e10f
#define GAMMA_ 0.1f
#define INVG 10.0f
#define KQTSE_ 0.1f

__device__ __forceinline__ float softmin3(float a, float b, float c) {
    float m = fminf(a, fminf(b, c));
    float s = __expf((m - a) * INVG) + __expf((m - b) * INVG) + __expf((m - c) * INVG);
    return m - GAMMA_ * __logf(s);
}

// One block per batch element. Thread j owns column j. Anti-diagonal wavefront.
// R values live in registers (own column) + 3-deep rotating LDS buffer for the
// left-neighbor column (j-1). One barrier per diagonal.
__global__ __launch_bounds__(1024) void sdtw_kernel(const float* __restrict__ pred,
                                                    const float* __restrict__ targ,
                                                    float* __restrict__ sdtw_out) {
    __shared__ float p[T];
    __shared__ float buf[3][T];
    const int b = blockIdx.x;
    const int j = threadIdx.x;

    p[j] = pred[b * T + j];
    const float tj = targ[b * T + j];
    __syncthreads();

    float r_prev1 = BIGF;  // value this thread computed on previous diagonal: R[i-1][j]

    for (int d = 0; d < 2 * T - 1; ++d) {
        const int i0 = d - j;  // 0-based row this thread computes on diagonal d
        if (i0 >= 0 && i0 < T) {
            const float diff = p[i0] - tj;
            const float Dij = diff * diff;
            float rd, ru, rl;
            ru = (i0 == 0) ? BIGF : r_prev1;                  // R[i-1][j]
            if (j == 0) {
                rl = BIGF;                                     // R[i][j-1] at boundary
                rd = (i0 == 0) ? 0.0f : BIGF;                  // R[i-1][j-1] at boundary
            } else {
                rl = buf[(d + 2) % 3][j - 1];                  // (d-1)%3: neighbor, diag d-1
                rd = (i0 == 0) ? BIGF : buf[(d + 1) % 3][j - 1]; // (d-2)%3: neighbor, diag d-2
            }
            const float rnew = Dij + softmin3(rd, ru, rl);
            buf[d % 3][j] = rnew;
            r_prev1 = rnew;
        }
        __syncthreads();
    }

    if (j == T - 1) sdtw_out[b] = r_prev1;  // R[N][M]
}

// Single block: QTSE reduction over all B*T elements + combine with soft-DTW means.
__global__ __launch_bounds__(1024) void finish_kernel(const float* __restrict__ pred,
                                                      const float* __restrict__ targ,
                                                      const float* __restrict__ sdtw,
                                                      float* __restrict__ out) {
    const int tid = threadIdx.x;
    float acc = 0.0f;
    for (int idx = tid; idx < BATCH * T; idx += 1024) {
        const float e = pred[idx] - targ[idx];
        acc += e * e * __expf(KQTSE_ * e);
    }
    // wave-level reduce (wave64) then cross-wave via LDS
    for (int off = 32; off; off >>= 1) acc += __shfl_down(acc, off, 64);
    __shared__ float red[16];
    const int wave = tid >> 6, lane = tid & 63;
    if (lane == 0) red[wave] = acc;
    __syncthreads();
    if (tid == 0) {
        float q = 0.0f;
        for (int w = 0; w < 16; ++w) q += red[w];
        q /= (float)(BATCH * T);
        float s = 0.0f;
        for (int bb = 0; bb < BATCH; ++bb) s += sdtw[bb];
        s /= (float)BATCH;
        out[0] = 0.1f * s + 1.0f * q;
    }
}

extern "C" void kernel_launch(void* const* d_in, const int* in_sizes, int n_in,
                              void* d_out, int out_size, void* d_ws, size_t ws_size,
                              hipStream_t stream) {
    const float* pred = (const float*)d_in[0];
    const float* targ = (const float*)d_in[1];
    float* out = (float*)d_out;
    float* sdtw = (float*)d_ws;  // 32 floats of scratch

    sdtw_kernel<<<BATCH, T, 0, stream>>>(pred, targ, sdtw);
    finish_kernel<<<1, 1024, 0, stream>>>(pred, targ, sdtw, out);
}

// Round 2
// 590.814 us; speedup vs baseline: 1.2642x; 1.2642x over previous
//
#include <hip/hip_runtime.h>
#include <hip/hip_bf16.h>

#define BATCH 32
#define T 1024
#define C 4
#define R 4
#define NT (T / C)        // 256 threads (column strips)
#define NC (T / R)        // 256 row chunks
#define ND (NT + NC - 1)  // 511 diagonals
#define BIGF 1e10f
#define KQTSE_ 0.1f

// softmin_gamma(a,b,c), gamma=0.1:
//  m - g*ln(sum exp((m-x)/g)) computed in base-2: K = (1/g)*log2(e)
__device__ __forceinline__ float softmin3(float a, float b, float c) {
    const float K = 14.4269504089f;       // INVG * log2(e)
    const float NLN2G = -0.069314718056f; // -gamma * ln(2)
    float m = fminf(fminf(a, b), c);      // -> v_min3_f32
    float mk = m * K;
    float s = exp2f(fmaf(-K, a, mk)) + exp2f(fmaf(-K, b, mk)) + exp2f(fmaf(-K, c, mk));
    return fmaf(NLN2G, __log2f(s), m);
}

// One block per batch element. Thread j owns columns [4j, 4j+4). Rows processed
// in chunks of 4. Tile (ic, j) computed at diagonal d = ic + j; 4x4 cells in
// registers (fully unrolled), right-edge column exchanged via double-buffered
// LDS. One barrier per diagonal: 511 barriers over 4 waves (was 2047 over 16).
__global__ __launch_bounds__(NT) void sdtw_kernel(const float* __restrict__ pred,
                                                  const float* __restrict__ targ,
                                                  float* __restrict__ sdtw_out) {
    __shared__ float p[T];
    __shared__ float edge[2][NT][4];   // [parity][thread][row-of-chunk]

    const int b = blockIdx.x;
    const int j = threadIdx.x;

    ((float4*)p)[j] = ((const float4*)(pred + b * T))[j];
    const float4 t4 = ((const float4*)(targ + b * T))[j];
    const float tj[4] = {t4.x, t4.y, t4.z, t4.w};

    float top[4];      // bottom row of my previous chunk: cells (i_top-1, 4j..4j+3)
    float corner = 0.0f;   // cell (i_top-1, 4j-1)
    float result = 0.0f;

    __syncthreads();

    for (int d = 0; d < ND; ++d) {
        const int ic = d - j;
        if (ic >= 0 && ic < NC) {
            // left column: cells (4ic..4ic+3, 4j-1), written by thread j-1 at diagonal d-1
            float lf[4];
            if (j == 0) {
                lf[0] = lf[1] = lf[2] = lf[3] = BIGF;
            } else {
                const float4 e = *(const float4*)&edge[(d + 1) & 1][j - 1][0];
                lf[0] = e.x; lf[1] = e.y; lf[2] = e.z; lf[3] = e.w;
            }
            float corner_cur;
            if (ic == 0) {
                top[0] = top[1] = top[2] = top[3] = BIGF;   // R[0][col>=1] = BIG
                corner_cur = (j == 0) ? 0.0f : BIGF;        // R[0][0]=0 else BIG
            } else {
                corner_cur = corner;
            }
            const float4 p4v = *(const float4*)&p[ic * R];
            const float p4[4] = {p4v.x, p4v.y, p4v.z, p4v.w};

            float cur[R][C];
#pragma unroll
            for (int r = 0; r < R; ++r) {
#pragma unroll
                for (int c = 0; c < C; ++c) {
                    const float up = (r == 0) ? top[c] : cur[r - 1][c];
                    const float dg = (r == 0) ? ((c == 0) ? corner_cur : top[c - 1])
                                              : ((c == 0) ? lf[r - 1] : cur[r - 1][c - 1]);
                    const float lt = (c == 0) ? lf[r] : cur[r][c - 1];
                    const float diff = p4[r] - tj[c];
                    cur[r][c] = fmaf(diff, diff, softmin3(dg, up, lt));
                }
            }
            // publish my right edge for thread j+1 (read at diagonal d+1)
            *(float4*)&edge[d & 1][j][0] =
                make_float4(cur[0][3], cur[1][3], cur[2][3], cur[3][3]);
#pragma unroll
            for (int c = 0; c < C; ++c) top[c] = cur[3][c];
            corner = lf[3];        // cell (4ic+3, 4j-1) = diag corner for next chunk
            result = cur[3][3];
        }
        __syncthreads();
    }

    if (j == NT - 1) sdtw_out[b] = result;   // cell (1023,1023) = R[N][M]
}

// Single block: QTSE reduction over all B*T elements + combine.
__global__ __launch_bounds__(1024) void finish_kernel(const float* __restrict__ pred,
                                                      const float* __restrict__ targ,
                                                      const float* __restrict__ sdtw,
                                                      float* __restrict__ out) {
    const int tid = threadIdx.x;
    float acc = 0.0f;
    for (int idx = tid; idx < BATCH * T; idx += 1024) {
        const float e = pred[idx] - targ[idx];
        acc += e * e * __expf(KQTSE_ * e);
    }
    for (int off = 32; off; off >>= 1) acc += __shfl_down(acc, off, 64);
    __shared__ float red[16];
    const int wave = tid >> 6, lane = tid & 63;
    if (lane == 0) red[wave] = acc;
    __syncthreads();
    if (tid == 0) {
        float q = 0.0f;
        for (int w = 0; w < 16; ++w) q += red[w];
        q /= (float)(BATCH * T);
        float s = 0.0f;
        for (int bb = 0; bb < BATCH; ++bb) s += sdtw[bb];
        s /= (float)BATCH;
        out[0] = 0.1f * s + 1.0f * q;
    }
}

extern "C" void kernel_launch(void* const* d_in, const int* in_sizes, int n_in,
                              void* d_out, int out_size, void* d_ws, size_t ws_size,
                              hipStream_t stream) {
    const float* pred = (const float*)d_in[0];
    const float* targ = (const float*)d_in[1];
    float* out = (float*)d_out;
    float* sdtw = (float*)d_ws;   // 32 floats of scratch

    sdtw_kernel<<<BATCH, NT, 0, stream>>>(pred, targ, sdtw);
    finish_kernel<<<1, 1024, 0, stream>>>(pred, targ, sdtw, out);
}

// Round 4
// 479.141 us; speedup vs baseline: 1.5588x; 1.2331x over previous
//
#include <hip/hip_runtime.h>
#include <hip/hip_bf16.h>

#define BATCH 32
#define T 1024
#define C 2
#define R 2
#define NT (T / C)        // 512 threads (column strips of 2)
#define NC (T / R)        // 512 row chunks of 2
#define ND (NT + NC - 1)  // 1023 diagonals
#define BIGF 1e10f
#define K2f 14.426950408889634f    // 1/(gamma*ln2), gamma=0.1
#define GLN2f 0.0693147180559945f  // gamma*ln2
#define KQTSE_ 0.1f

// Exact softmin_gamma(a,b,c), gamma=0.1, in base-2:
// m - g*ln(e^{(m-a)/g}+e^{(m-b)/g}+e^{(m-c)/g}) ; one term is exactly 1.
__device__ __forceinline__ float softmin3(float a, float b, float c) {
    float m = fminf(fminf(a, b), c);          // -> v_min3_f32
    float mk = m * K2f;
    float s = exp2f(fmaf(-K2f, a, mk)) + exp2f(fmaf(-K2f, b, mk)) + exp2f(fmaf(-K2f, c, mk));
    return fmaf(-GLN2f, __log2f(s), m);
}

// One block per batch element, 512 threads. Thread j owns columns [2j, 2j+2);
// rows in chunks of 2. Tile (ic,j) at diagonal d = ic+j; 2x2 cells in registers
// (exact R-space), right-edge column exchanged via double-buffered planar LDS.
// 8 waves/block -> 2 waves/SIMD busy mid-kernel: latency hiding that the
// 256-thread version (1 wave/SIMD) completely lacked.
__global__ __launch_bounds__(NT) void sdtw_kernel(const float* __restrict__ pred,
                                                  const float* __restrict__ targ,
                                                  float* __restrict__ sdtw_out) {
    __shared__ float p[T];
    __shared__ float edge[R][2][NT];   // [row][parity][thread]: stride-1 b32, conflict-free

    const int b = blockIdx.x;
    const int j = threadIdx.x;

    ((float2*)p)[j] = ((const float2*)(pred + b * T))[j];
    const float2 t2v = ((const float2*)(targ + b * T))[j];
    const float tj0 = t2v.x, tj1 = t2v.y;

    float top0 = BIGF, top1 = BIGF;  // R-space bottom row of my previous chunk
    float corner = 0.0f;             // R-space cell (2ic-1, 2j-1)
    float result = 0.0f;

    __syncthreads();

    for (int d = 0; d < ND; ++d) {
        const int ic = d - j;
        if (ic >= 0 && ic < NC) {
            // left column cells (2ic, 2j-1), (2ic+1, 2j-1) from thread j-1 (diag d-1)
            float lf0, lf1;
            if (j == 0) {
                lf0 = BIGF; lf1 = BIGF;
            } else {
                const int par = (d + 1) & 1;
                lf0 = edge[0][par][j - 1];
                lf1 = edge[1][par][j - 1];
            }
            float corner_cur;
            if (ic == 0) {
                top0 = BIGF; top1 = BIGF;
                corner_cur = (j == 0) ? 0.0f : BIGF;   // R[0][0]=0, else boundary BIG
            } else {
                corner_cur = corner;
            }
            const float2 pv = *(const float2*)&p[ic * R];

            // cell (r0,c0): up=top0 dg=corner lt=lf0
            const float d00 = pv.x - tj0;
            const float c00 = fmaf(d00, d00, softmin3(corner_cur, top0, lf0));
            // cell (r0,c1): up=top1 dg=top0 lt=c00
            const float d01 = pv.x - tj1;
            const float c01 = fmaf(d01, d01, softmin3(top0, top1, c00));
            // cell (r1,c0): up=c00 dg=lf0 lt=lf1
            const float d10 = pv.y - tj0;
            const float c10 = fmaf(d10, d10, softmin3(lf0, c00, lf1));
            // cell (r1,c1): up=c01 dg=c00 lt=c10
            const float d11 = pv.y - tj1;
            const float c11 = fmaf(d11, d11, softmin3(c00, c01, c10));

            edge[0][d & 1][j] = c01;   // right edge rows 0,1 (col 2j+1)
            edge[1][d & 1][j] = c11;
            top0 = c10; top1 = c11;    // bottom row for my next chunk
            corner = lf1;              // cell (2ic+1, 2j-1)
            result = c11;
        }
        __syncthreads();
    }

    if (j == NT - 1) sdtw_out[b] = result;   // cell (1023,1023)
}

// Single block: QTSE reduction over all B*T elements + combine.
__global__ __launch_bounds__(1024) void finish_kernel(const float* __restrict__ pred,
                                                      const float* __restrict__ targ,
                                                      const float* __restrict__ sdtw,
                                                      float* __restrict__ out) {
    const int tid = threadIdx.x;
    float acc = 0.0f;
    for (int idx = tid; idx < BATCH * T; idx += 1024) {
        const float e = pred[idx] - targ[idx];
        acc += e * e * __expf(KQTSE_ * e);
    }
    for (int off = 32; off; off >>= 1) acc += __shfl_down(acc, off, 64);
    __shared__ float red[16];
    const int wave = tid >> 6, lane = tid & 63;
    if (lane == 0) red[wave] = acc;
    __syncthreads();
    if (tid == 0) {
        float q = 0.0f;
        for (int w = 0; w < 16; ++w) q += red[w];
        q /= (float)(BATCH * T);
        float s = 0.0f;
        for (int bb = 0; bb < BATCH; ++bb) s += sdtw[bb];
        s /= (float)BATCH;
        out[0] = 0.1f * s + 1.0f * q;
    }
}

extern "C" void kernel_launch(void* const* d_in, const int* in_sizes, int n_in,
                              void* d_out, int out_size, void* d_ws, size_t ws_size,
                              hipStream_t stream) {
    const float* pred = (const float*)d_in[0];
    const float* targ = (const float*)d_in[1];
    float* out = (float*)d_out;
    float* sdtw = (float*)d_ws;   // 32 floats of scratch

    sdtw_kernel<<<BATCH, NT, 0, stream>>>(pred, targ, sdtw);
    finish_kernel<<<1, 1024, 0, stream>>>(pred, targ, sdtw, out);
}

// Round 5
// 472.425 us; speedup vs baseline: 1.5810x; 1.0142x over previous
//
#include <hip/hip_runtime.h>
#include <hip/hip_bf16.h>

#define BATCH 32
#define T 1024
#define WAVES 8
#define NTH (WAVES * 64)          // 512 threads
#define RR 2                      // rows per chunk
#define NC (T / RR)               // 512 chunks per column strip
#define KS 8                      // steps between barriers
#define DOW (63 + KS)             // 71: inter-wave step offset (lane skew + sync quantum)
#define TOT (DOW * (WAVES - 1) + 63 + NC)   // 497 + 63 + 512 = 1072
#define NB (TOT / KS)             // 134 barrier windows (1072 % 8 == 0)
#define BIGF 1e10f
#define K2f 14.426950408889634f   // 1/(gamma*ln2), gamma=0.1
#define GLN2f 0.0693147180559945f // gamma*ln2
#define KQTSE_ 0.1f

// Exact softmin_gamma(a,b,c), gamma=0.1, base-2; one exp term is exactly 1.
__device__ __forceinline__ float softmin3(float a, float b, float c) {
    float m = fminf(fminf(a, b), c);          // -> v_min3_f32
    float mk = m * K2f;
    float s = exp2f(fmaf(-K2f, a, mk)) + exp2f(fmaf(-K2f, b, mk)) + exp2f(fmaf(-K2f, c, mk));
    return fmaf(-GLN2f, __log2f(s), m);
}

// Skewed-wave systolic soft-DTW. One block per batch element, 8 waves.
// Thread (wave w, lane l) owns columns [2*tid, 2*tid+2); it processes row-chunk
// ic (rows 2ic..2ic+1) at step s = ic + l + 71*w. Left edges for lanes 1..63
// come from lane l-1's previous-step registers via __shfl_up (no LDS, no
// barrier: wave lockstep). Wave boundary (lane 63 -> next wave's lane 0) goes
// through a full-size LDS ring; the 71-step inter-wave lag = 63 (lane skew)
// + 8 (sync quantum) guarantees that ONE __syncthreads() every 8 steps orders
// every ring write before its read. Lane 0 batch-prefetches the 8 ring entries
// its window needs right after each barrier (all provably visible by then).
__global__ __launch_bounds__(NTH) void sdtw_kernel(const float* __restrict__ pred,
                                                   const float* __restrict__ targ,
                                                   float* __restrict__ sdtw_out) {
    __shared__ float p[T];
    __shared__ float ring[WAVES - 1][NC][2];   // 28 KB: right-edge pairs per interface

    const int b = blockIdx.x;
    const int tid = threadIdx.x;
    const int wv = tid >> 6;
    const int ln = tid & 63;
    const int myoff = DOW * wv + ln;

    ((float2*)p)[tid] = ((const float2*)(pred + b * T))[tid];
    const float2 t2v = ((const float2*)(targ + b * T))[tid];
    const float tj0 = t2v.x, tj1 = t2v.y;

    float top0 = BIGF, top1 = BIGF;   // bottom row of my previous chunk
    float cornerR = BIGF;             // cell (2ic-1, left-1)
    float rc0 = BIGF, rc1 = BIGF;     // my right-edge column from the previous step
    float result = 0.0f;

    __syncthreads();

    for (int sb = 0; sb < NB; ++sb) {
        const int ics = sb * KS - myoff;   // my chunk index at so = 0

        float2 rl[KS];
#pragma unroll
        for (int so = 0; so < KS; ++so) rl[so] = make_float2(BIGF, BIGF);
        if (wv > 0 && ln == 0) {
#pragma unroll
            for (int so = 0; so < KS; ++so) {
                int icc = ics + so;
                icc = icc < 0 ? 0 : (icc >= NC ? NC - 1 : icc);
                rl[so] = *(const float2*)&ring[wv - 1][icc][0];   // garbage if clamped: unused
            }
        }

#pragma unroll
        for (int so = 0; so < KS; ++so) {
            const int ic = ics + so;
            // left edge: lane l-1's right column from the previous step
            const float s0 = __shfl_up(rc0, 1, 64);
            const float s1 = __shfl_up(rc1, 1, 64);
            const float lf0 = (ln == 0) ? rl[so].x : s0;
            const float lf1 = (ln == 0) ? rl[so].y : s1;

            if (ic >= 0 && ic < NC) {
                float cc;
                if (ic == 0) {
                    top0 = BIGF; top1 = BIGF;
                    cc = (tid == 0) ? 0.0f : BIGF;   // R[0][0]=0, else boundary BIG
                } else {
                    cc = cornerR;
                }
                const float2 pv = ((const float2*)p)[ic];

                // 2x2 tile, exact R-space (identical numerics to the passing R4 kernel)
                const float d00 = pv.x - tj0;
                const float c00 = fmaf(d00, d00, softmin3(cc, top0, lf0));
                const float d01 = pv.x - tj1;
                const float c01 = fmaf(d01, d01, softmin3(top0, top1, c00));
                const float d10 = pv.y - tj0;
                const float c10 = fmaf(d10, d10, softmin3(lf0, c00, lf1));
                const float d11 = pv.y - tj1;
                const float c11 = fmaf(d11, d11, softmin3(c00, c01, c10));

                rc0 = c01; rc1 = c11;         // right edge for lane l+1 (next step's shfl)
                top0 = c10; top1 = c11;
                cornerR = lf1;                // cell (2ic+1, left-1): next chunk's corner
                result = c11;

                if (ln == 63 && wv < WAVES - 1) {
                    *(float2*)&ring[wv][ic][0] = make_float2(c01, c11);
                }
            }
        }
        __syncthreads();   // publishes this window's ring writes for the next window
    }

    if (tid == NTH - 1) sdtw_out[b] = result;   // cell (1023,1023)
}

// Single block: QTSE reduction over all B*T elements + combine.
__global__ __launch_bounds__(1024) void finish_kernel(const float* __restrict__ pred,
                                                      const float* __restrict__ targ,
                                                      const float* __restrict__ sdtw,
                                                      float* __restrict__ out) {
    const int tid = threadIdx.x;
    float acc = 0.0f;
    for (int idx = tid; idx < BATCH * T; idx += 1024) {
        const float e = pred[idx] - targ[idx];
        acc += e * e * __expf(KQTSE_ * e);
    }
    for (int off = 32; off; off >>= 1) acc += __shfl_down(acc, off, 64);
    __shared__ float red[16];
    const int wave = tid >> 6, lane = tid & 63;
    if (lane == 0) red[wave] = acc;
    __syncthreads();
    if (tid == 0) {
        float q = 0.0f;
        for (int w = 0; w < 16; ++w) q += red[w];
        q /= (float)(BATCH * T);
        float s = 0.0f;
        for (int bb = 0; bb < BATCH; ++bb) s += sdtw[bb];
        s /= (float)BATCH;
        out[0] = 0.1f * s + 1.0f * q;
    }
}

extern "C" void kernel_launch(void* const* d_in, const int* in_sizes, int n_in,
                              void* d_out, int out_size, void* d_ws, size_t ws_size,
                              hipStream_t stream) {
    const float* pred = (const float*)d_in[0];
    const float* targ = (const float*)d_in[1];
    float* out = (float*)d_out;
    float* sdtw = (float*)d_ws;   // 32 floats of scratch

    sdtw_kernel<<<BATCH, NTH, 0, stream>>>(pred, targ, sdtw);
    finish_kernel<<<1, 1024, 0, stream>>>(pred, targ, sdtw, out);
}

// Round 6
// 375.918 us; speedup vs baseline: 1.9868x; 1.2567x over previous
//
#include <hip/hip_runtime.h>
#include <hip/hip_bf16.h>

#define BATCH 32
#define T 1024
#define WAVES 8
#define NTH (WAVES * 64)          // 512 threads, thread owns 2 columns
#define NCR 1024                  // row chunks (1 row per step)
#define KS 8                      // steps between barriers
#define DOW (63 + KS)             // 71: inter-wave step offset
#define TOT (DOW * (WAVES - 1) + 63 + NCR)   // 497 + 63 + 1024 = 1584
#define NB (TOT / KS)             // 198 barrier windows (1584 % 8 == 0)
#define BIGF 1e10f
#define K2f 14.426950408889634f   // 1/(gamma*ln2), gamma=0.1
#define GLN2f 0.0693147180559945f // gamma*ln2
#define KQTSE_ 0.1f

// Exact softmin_gamma(a,b,c) via sorted args: with m=min, md=med, M=max,
//   softmin = m - g*ln(1 + e^{(m-md)/g} + e^{(m-M)/g})
// One exp is folded analytically (exp(0)=1): 2x exp2 + 1x log2 per cell
// (vs 3+1), min3/med3/max3 are single full-rate VALU ops.
__device__ __forceinline__ float softmin3(float a, float b, float c) {
    float m  = fminf(fminf(a, b), c);                 // v_min3_f32
    float M  = fmaxf(fmaxf(a, b), c);                 // v_max3_f32
    float md = __builtin_amdgcn_fmed3f(a, b, c);      // v_med3_f32
    float e1 = exp2f((m - md) * K2f);
    float e2 = exp2f((m - M) * K2f);
    float s  = 1.0f + e1 + e2;
    return fmaf(-GLN2f, __log2f(s), m);
}

// Skewed-wave systolic soft-DTW, 1 row x 2 cols per thread-step.
// Thread (wave w, lane l) owns columns [2*tid, 2*tid+2); it processes row ic
// at step s = ic + l + 71*w. Left edge for lanes 1..63: lane l-1's previous-
// step right edge via __shfl_up (wave lockstep). Wave boundary via full-size
// LDS ring; 71-step lag = 63 (lane skew) + 8 (sync quantum) makes ONE
// __syncthreads() per 8 steps sufficient ordering. Busy fraction 1024/1584
// = 65% (vs 48% at 2 rows/step).
__global__ __launch_bounds__(NTH) void sdtw_kernel(const float* __restrict__ pred,
                                                   const float* __restrict__ targ,
                                                   float* __restrict__ sdtw_out) {
    __shared__ float p[T];
    __shared__ float ring[WAVES - 1][NCR];   // 28 KB: right-edge value per interface row

    const int b = blockIdx.x;
    const int tid = threadIdx.x;
    const int wv = tid >> 6;
    const int ln = tid & 63;
    const int myoff = DOW * wv + ln;

    ((float2*)p)[tid] = ((const float2*)(pred + b * T))[tid];
    const float2 t2v = ((const float2*)(targ + b * T))[tid];
    const float tj0 = t2v.x, tj1 = t2v.y;

    float top0 = BIGF, top1 = BIGF;   // my previous row's two cells
    float cornerR = BIGF;             // cell (i-1, 2*tid-1)
    float rc = BIGF;                  // my right edge from the previous step
    float result = 0.0f;

    __syncthreads();

    for (int sb = 0; sb < NB; ++sb) {
        const int ics = sb * KS - myoff;   // my row index at so = 0

        float rl[KS];
#pragma unroll
        for (int so = 0; so < KS; ++so) rl[so] = BIGF;
        if (wv > 0 && ln == 0) {
#pragma unroll
            for (int so = 0; so < KS; ++so) {
                int icc = ics + so;
                icc = icc < 0 ? 0 : (icc >= NCR ? NCR - 1 : icc);
                rl[so] = ring[wv - 1][icc];   // garbage if clamped: provably unused
            }
        }

#pragma unroll
        for (int so = 0; so < KS; ++so) {
            const int ic = ics + so;
            const float sh = __shfl_up(rc, 1, 64);
            const float lf0 = (ln == 0) ? rl[so] : sh;   // cell (ic, 2*tid-1)

            if (ic >= 0 && ic < NCR) {
                float t0, t1, cc;
                if (ic == 0) {
                    t0 = BIGF; t1 = BIGF;
                    cc = (tid == 0) ? 0.0f : BIGF;   // R[0][0]=0, else boundary BIG
                } else {
                    t0 = top0; t1 = top1; cc = cornerR;
                }
                const float pr = p[ic];

                // two cells of row ic, exact R-space
                const float d0 = pr - tj0;
                const float c00 = fmaf(d0, d0, softmin3(cc, t0, lf0));
                const float d1 = pr - tj1;
                const float c01 = fmaf(d1, d1, softmin3(t0, t1, c00));

                rc = c01;                 // right edge for lane l+1 next step
                top0 = c00; top1 = c01;   // become "up" for my next row
                cornerR = lf0;            // cell (ic, 2*tid-1): next row's corner
                result = c01;

                if (ln == 63 && wv < WAVES - 1) ring[wv][ic] = c01;
            }
        }
        __syncthreads();   // publishes this window's ring writes for the next window
    }

    if (tid == NTH - 1) sdtw_out[b] = result;   // cell (1023,1023)
}

// Single block: QTSE reduction over all B*T elements + combine.
__global__ __launch_bounds__(1024) void finish_kernel(const float* __restrict__ pred,
                                                      const float* __restrict__ targ,
                                                      const float* __restrict__ sdtw,
                                                      float* __restrict__ out) {
    const int tid = threadIdx.x;
    float acc = 0.0f;
    for (int idx = tid; idx < BATCH * T; idx += 1024) {
        const float e = pred[idx] - targ[idx];
        acc += e * e * __expf(KQTSE_ * e);
    }
    for (int off = 32; off; off >>= 1) acc += __shfl_down(acc, off, 64);
    __shared__ float red[16];
    const int wave = tid >> 6, lane = tid & 63;
    if (lane == 0) red[wave] = acc;
    __syncthreads();
    if (tid == 0) {
        float q = 0.0f;
        for (int w = 0; w < 16; ++w) q += red[w];
        q /= (float)(BATCH * T);
        float s = 0.0f;
        for (int bb = 0; bb < BATCH; ++bb) s += sdtw[bb];
        s /= (float)BATCH;
        out[0] = 0.1f * s + 1.0f * q;
    }
}

extern "C" void kernel_launch(void* const* d_in, const int* in_sizes, int n_in,
                              void* d_out, int out_size, void* d_ws, size_t ws_size,
                              hipStream_t stream) {
    const float* pred = (const float*)d_in[0];
    const float* targ = (const float*)d_in[1];
    float* out = (float*)d_out;
    float* sdtw = (float*)d_ws;   // 32 floats of scratch

    sdtw_kernel<<<BATCH, NTH, 0, stream>>>(pred, targ, sdtw);
    finish_kernel<<<1, 1024, 0, stream>>>(pred, targ, sdtw, out);
}